// Round 5
// baseline (166.284 us; speedup 1.0000x reference)
//
#include <hip/hip_runtime.h>

// DiffusionMLS: out[row[e]] += w[e]*(u[col[e]] - u[row[e]]), F=32 fp32.
// Round 19: node_half single global csr pass via REGISTER stash.
//  - r18 = 166us (best). node_half still read csr twice (hist pass + permute
//    pass, 2x12.8MB + two latency chains). r16's LDS sin_ fix cost occupancy
//    (43KB -> 3 blk/CU, regressed). Fix per rule #20: cnt<=HCAP=2560 -> 5
//    uint2/thread register stash, statically indexed (#pragma unroll).
//    LDS stays 22.5KB -> 4 blk/CU preserved; VGPR ~40->~52 (no cliff).
//  - everything else unchanged from r18:
//    1) hist+ticket-zero  2) fill multisplit + conv backfill blocks  3) node.

#define NFEAT 32
#define BUCKET_BITS 7
#define HB 128               // nodes per segment; rowLow fits 7 bits
#define MAXNB 1024           // bucket cell count (NBH <= 1023)
#define CH 4096              // edges per fill chunk (multiple of 512)
#define HCAP 2560            // node-phase staging cap (= 5 * 512)
#define KSTASH (HCAP / 512)  // register stash depth
#define HBLK 64              // histogram partial blocks

typedef float nfloat4 __attribute__((ext_vector_type(4)));
typedef unsigned int nuint2 __attribute__((ext_vector_type(2)));

__device__ __forceinline__ float4 nt_load_f4(const float4* p) {
    nfloat4 v = __builtin_nontemporal_load((const nfloat4*)p);
    return make_float4(v.x, v.y, v.z, v.w);
}
__device__ __forceinline__ void nt_store_f4(float4* p, float4 v) {
    nfloat4 t = {v.x, v.y, v.z, v.w};
    __builtin_nontemporal_store(t, (nfloat4*)p);
}
__device__ __forceinline__ uint2 nt_load_u2(const uint2* p) {
    nuint2 v = __builtin_nontemporal_load((const nuint2*)p);
    uint2 r; r.x = v.x; r.y = v.y; return r;
}

// wave64 inclusive scan, no barriers
__device__ __forceinline__ int wave_incl_scan(int v, int lane) {
#pragma unroll
    for (int off = 1; off < 64; off <<= 1) {
        int t = __shfl_up(v, off, 64);
        if (lane >= off) v += t;
    }
    return v;
}

// ---- dispatch 1: 64 private histograms + ticket zeroing ----
__global__ __launch_bounds__(512) void hist_kernel(const int* __restrict__ row,
                                                   int* __restrict__ hist_part,
                                                   int* __restrict__ ticket,
                                                   int E) {
    __shared__ int h[MAXNB];
    int hb = blockIdx.x;
    if (hb == 0) {                      // zero-based tickets for fill phase
        ticket[threadIdx.x] = 0;
        ticket[threadIdx.x + 512] = 0;
    }
    for (int i = threadIdx.x; i < MAXNB; i += 512) h[i] = 0;
    __syncthreads();
    int stride = HBLK * 512;
    for (int e = hb * 512 + threadIdx.x; e < E; e += stride)
        atomicAdd(&h[__builtin_nontemporal_load(&row[e]) >> BUCKET_BITS], 1);
    __syncthreads();
    int* dst = hist_part + (size_t)hb * MAXNB;
    for (int i = threadIdx.x; i < MAXNB; i += 512) dst[i] = h[i];   // plain store
}

// ---- dispatch 2: fill blocks [0,nChunks) + conv blocks [nChunks, +convBlocks)
__global__ __launch_bounds__(512) void fill_conv_kernel(const int* __restrict__ row,
                                                        const int* __restrict__ col,
                                                        const float* __restrict__ w,
                                                        const int* __restrict__ hist_part,
                                                        int* __restrict__ ticket,
                                                        int* __restrict__ offsets,
                                                        uint2* __restrict__ csr,
                                                        const float4* __restrict__ u4,
                                                        ushort4* __restrict__ ub,
                                                        int n4, int E, int nChunks) {
    __shared__ int hist[MAXNB];           // 4K
    __shared__ int sc[MAXNB];             // 4K
    __shared__ int gb0[MAXNB];            // 4K
    __shared__ int wsumL[8];
    __shared__ int wsumG[8];
    __shared__ uint2 so[CH];              // 32K
    __shared__ unsigned short sbs[CH];    // 8K

    if ((int)blockIdx.x >= nChunks) {     // ---- conv block (pure streaming)
        int i = ((int)blockIdx.x - nChunks) * 512 + threadIdx.x;
        if (i < n4) {
            float4 v = nt_load_f4(&u4[i]);
            ushort4 o;
            unsigned x;
            x = __float_as_uint(v.x); x += 0x7fffu + ((x >> 16) & 1u); o.x = (unsigned short)(x >> 16);
            x = __float_as_uint(v.y); x += 0x7fffu + ((x >> 16) & 1u); o.y = (unsigned short)(x >> 16);
            x = __float_as_uint(v.z); x += 0x7fffu + ((x >> 16) & 1u); o.z = (unsigned short)(x >> 16);
            x = __float_as_uint(v.w); x += 0x7fffu + ((x >> 16) & 1u); o.w = (unsigned short)(x >> 16);
            ub[i] = o;
        }
        return;
    }

    int tid = threadIdx.x;
    int lane = tid & 63, wid = tid >> 6;
    int lo = blockIdx.x * CH;
    int n = min(E - lo, CH);
    bool full = (n == CH);

    hist[tid] = 0;
    hist[tid + 512] = 0;
    __syncthreads();

    // -- local hist (+ register row stash for full chunks)
    int rst[CH / 512];                    // static idx only (rule #20)
    if (full) {
#pragma unroll
        for (int k = 0; k < CH / 512; ++k) {
            int r = __builtin_nontemporal_load(&row[lo + tid + k * 512]);
            rst[k] = r;
            atomicAdd(&hist[r >> BUCKET_BITS], 1);
        }
    } else {
        for (int i = tid; i < n; i += 512)
            atomicAdd(&hist[__builtin_nontemporal_load(&row[lo + i]) >> BUCKET_BITS], 1);
    }

    // -- redundant global partial sum (L2-resident 256 KB; overlaps hist tail)
    int c0g = 0, c1g = 0;
    for (int p = 0; p < HBLK; ++p) {
        int2 v = ((const int2*)(hist_part + (size_t)p * MAXNB))[tid];
        c0g += v.x; c1g += v.y;
    }
    __syncthreads();                      // local hist complete

    int c0 = hist[2 * tid];
    int c1 = hist[2 * tid + 1];
    int pairL = c0 + c1;
    int pairG = c0g + c1g;
    int inclL = wave_incl_scan(pairL, lane);
    int inclG = wave_incl_scan(pairG, lane);
    if (lane == 63) { wsumL[wid] = inclL; wsumG[wid] = inclG; }
    __syncthreads();
    int baseL = 0, baseG = 0;
#pragma unroll
    for (int i = 0; i < 8; ++i) {
        int vl = wsumL[i], vg = wsumG[i];
        if (i < wid) { baseL += vl; baseG += vg; }
    }
    inclL += baseL;
    inclG += baseG;
    int exclL = inclL - pairL;
    sc[2 * tid] = exclL;
    sc[2 * tid + 1] = exclL + c0;
    int gE0 = inclG - pairG;              // global exclusive offset, cell 2t
    int gE1 = gE0 + c0g;                  // cell 2t+1

    if (blockIdx.x == 0) {                // offsets for node phase
        offsets[2 * tid] = gE0;
        offsets[2 * tid + 1] = gE1;
        if (tid == 511) offsets[MAXNB] = inclG;   // = E
    }

    int g0 = gE0 + (c0 ? atomicAdd(&ticket[2 * tid], c0) : 0);
    int g1 = gE1 + (c1 ? atomicAdd(&ticket[2 * tid + 1], c1) : 0);
    gb0[2 * tid] = g0;
    gb0[2 * tid + 1] = g1;
    hist[2 * tid] = g0;                   // arrival cursor
    hist[2 * tid + 1] = g1;
    __syncthreads();

    // -- multisplit into LDS staging
    if (full) {
#pragma unroll
        for (int k = 0; k < CH / 512; ++k) {
            int i = tid + k * 512;
            int r = rst[k];
            unsigned c = (unsigned)__builtin_nontemporal_load(&col[lo + i]);
            float wt = __builtin_nontemporal_load(&w[lo + i]);
            int b = r >> BUCKET_BITS;
            uint2 p;
            p.x = ((unsigned)(r & (HB - 1)) << 25) | c;   // rowLow:7 | col:25
            p.y = __float_as_uint(wt);
            int d = atomicAdd(&hist[b], 1);
            int pos = sc[b] + (d - gb0[b]);
            so[pos] = p;
            sbs[pos] = (unsigned short)b;
        }
    } else {
        for (int i = tid; i < n; i += 512) {
            int r = __builtin_nontemporal_load(&row[lo + i]);
            unsigned c = (unsigned)__builtin_nontemporal_load(&col[lo + i]);
            float wt = __builtin_nontemporal_load(&w[lo + i]);
            int b = r >> BUCKET_BITS;
            uint2 p;
            p.x = ((unsigned)(r & (HB - 1)) << 25) | c;
            p.y = __float_as_uint(wt);
            int d = atomicAdd(&hist[b], 1);
            int pos = sc[b] + (d - gb0[b]);
            so[pos] = p;
            sbs[pos] = (unsigned short)b;
        }
    }
    __syncthreads();

    // -- coalesced-run writeout
    for (int i = tid; i < n; i += 512) {
        int b = sbs[i];
        csr[gb0[b] + (i - sc[b])] = so[i];
    }
}

// ---- dispatch 3: per-segment counting sort + register accumulation ----
//      single global csr pass: 5x uint2 register stash (static idx, rule #20)
__global__ __launch_bounds__(512) void node_half_kernel(const ushort4* __restrict__ ub,
                                                        const float4* __restrict__ u4,
                                                        const int* __restrict__ offsets,
                                                        const uint2* __restrict__ csr,
                                                        float4* __restrict__ out4, int N) {
    __shared__ uint2 se[HCAP];          // 20.5 KB (fallback: f32 tile 16 KB)
    __shared__ int hist[HB];
    __shared__ int starts[HB + 1];
    __shared__ int sc[HB];

    int b = blockIdx.x;
    int tid = threadIdx.x;
    int start = offsets[b];
    int end = offsets[b + 1];
    int cnt = end - start;

    if (tid < HB) hist[tid] = 0;
    __syncthreads();

    if (cnt <= HCAP) {
        uint2 rst[KSTASH];              // csr register stash
#pragma unroll
        for (int k = 0; k < KSTASH; ++k) {
            int i = start + tid + k * 512;
            if (i < end) {
                uint2 p = nt_load_u2(&csr[i]);
                rst[k] = p;
                atomicAdd(&hist[p.x >> 25], 1);
            }
        }
        __syncthreads();
        int myc = (tid < HB) ? hist[tid] : 0;
        int lane = tid & 63;
        int incl = wave_incl_scan(myc, lane);
        if (lane == 63) sc[tid >> 6] = incl;   // only waves 0-1 carry real data
        __syncthreads();
        if (tid < HB) {
            if (tid >= 64) incl += sc[0];
            int excl = incl - myc;
            starts[tid] = excl;
            hist[tid] = excl;       // cursor
            if (tid == HB - 1) starts[HB] = incl;
        }
        __syncthreads();
#pragma unroll
        for (int k = 0; k < KSTASH; ++k) {
            int i = start + tid + k * 512;
            if (i < end) {
                uint2 p = rst[k];
                int pos = atomicAdd(&hist[p.x >> 25], 1);
                se[pos] = p;
            }
        }
        __syncthreads();
        int wave = tid >> 6;
        int f4 = lane & 7;
        int slot = lane >> 3;
        for (int node = wave; node < HB; node += 8) {
            int s0 = starts[node];
            int s1 = starts[node + 1];
            float4 acc = make_float4(0.f, 0.f, 0.f, 0.f);
            float ws_ = 0.f;
            for (int i = s0 + slot; i < s1; i += 8) {
                uint2 p = se[i];
                int c = (int)(p.x & 0x01FFFFFFu);
                float wt = __uint_as_float(p.y);
                ushort4 us = ub[(size_t)c * 8 + f4];
                acc.x += wt * __uint_as_float((unsigned)us.x << 16);
                acc.y += wt * __uint_as_float((unsigned)us.y << 16);
                acc.z += wt * __uint_as_float((unsigned)us.z << 16);
                acc.w += wt * __uint_as_float((unsigned)us.w << 16);
                ws_ += wt;
            }
#pragma unroll
            for (int m = 8; m < 64; m <<= 1) {
                acc.x += __shfl_xor(acc.x, m, 64);
                acc.y += __shfl_xor(acc.y, m, 64);
                acc.z += __shfl_xor(acc.z, m, 64);
                acc.w += __shfl_xor(acc.w, m, 64);
                ws_   += __shfl_xor(ws_,   m, 64);
            }
            int glob = b * HB + node;
            if (slot == 0 && glob < N) {
                float4 ur = nt_load_f4(&u4[(size_t)glob * 8 + f4]);
                float4 o;
                o.x = acc.x - ws_ * ur.x;
                o.y = acc.y - ws_ * ur.y;
                o.z = acc.z - ws_ * ur.z;
                o.w = acc.w - ws_ * ur.w;
                nt_store_f4(&out4[(size_t)glob * 8 + f4], o);
            }
        }
    } else {
        float* tile = (float*)se;   // HB*32 floats
        float* wsumf = (float*)sc;
        for (int i = tid; i < HB * NFEAT; i += 512) tile[i] = 0.f;
        if (tid < HB) wsumf[tid] = 0.f;
        __syncthreads();
        int f4 = tid & 7;
        for (int i = start + (tid >> 3); i < end; i += 64) {
            uint2 p = nt_load_u2(&csr[i]);
            int rl = (int)(p.x >> 25);
            int c = (int)(p.x & 0x01FFFFFFu);
            float wt = __uint_as_float(p.y);
            ushort4 us = ub[(size_t)c * 8 + f4];
            float* t = &tile[rl * NFEAT + f4 * 4];
            atomicAdd(t + 0, wt * __uint_as_float((unsigned)us.x << 16));
            atomicAdd(t + 1, wt * __uint_as_float((unsigned)us.y << 16));
            atomicAdd(t + 2, wt * __uint_as_float((unsigned)us.z << 16));
            atomicAdd(t + 3, wt * __uint_as_float((unsigned)us.w << 16));
            if (f4 == 0) atomicAdd(&wsumf[rl], wt);
        }
        __syncthreads();
#pragma unroll
        for (int pass = 0; pass < 2; ++pass) {
            int idx = pass * 512 + tid;
            int node = idx >> 3;
            int ff = idx & 7;
            int glob = b * HB + node;
            if (glob < N) {
                float4 ur = nt_load_f4(&u4[(size_t)glob * 8 + ff]);
                float ws_ = wsumf[node];
                const float* t = &tile[node * NFEAT + ff * 4];
                float4 o;
                o.x = t[0] - ws_ * ur.x;
                o.y = t[1] - ws_ * ur.y;
                o.z = t[2] - ws_ * ur.z;
                o.w = t[3] - ws_ * ur.w;
                nt_store_f4(&out4[(size_t)glob * 8 + ff], o);
            }
        }
    }
}

// ---------------- fallback (atomic path) ----------------

__global__ __launch_bounds__(256) void zero_out_kernel(float* __restrict__ out, int n) {
    int i = blockIdx.x * blockDim.x + threadIdx.x;
    if (i < n) out[i] = 0.0f;
}

__global__ __launch_bounds__(256) void scatter_lap_kernel(const float4* __restrict__ u4,
                                                          const float* __restrict__ w,
                                                          const int* __restrict__ row,
                                                          const int* __restrict__ col,
                                                          float* __restrict__ out, int n_edges) {
    int tid = blockIdx.x * blockDim.x + threadIdx.x;
    int e = tid >> 3;
    int f4 = tid & 7;
    if (e >= n_edges) return;
    int r = row[e];
    int c = col[e];
    float wt = w[e];
    float4 uc = u4[(size_t)c * 8 + f4];
    float4 ur = u4[(size_t)r * 8 + f4];
    float* o = out + (size_t)r * NFEAT + f4 * 4;
    atomicAdd(o + 0, wt * (uc.x - ur.x));
    atomicAdd(o + 1, wt * (uc.y - ur.y));
    atomicAdd(o + 2, wt * (uc.z - ur.z));
    atomicAdd(o + 3, wt * (uc.w - ur.w));
}

extern "C" void kernel_launch(void* const* d_in, const int* in_sizes, int n_in,
                              void* d_out, int out_size, void* d_ws, size_t ws_size,
                              hipStream_t stream) {
    const float* u = (const float*)d_in[0];
    const float* w = (const float*)d_in[1];
    const int* ei = (const int*)d_in[2];  // [2, E] int32
    float* out = (float*)d_out;

    const int E = in_sizes[1];
    const int N = out_size / NFEAT;
    const int* row = ei;
    const int* col = ei + E;

    const int NBH = (N + HB - 1) >> BUCKET_BITS;

    // workspace layout (256-B aligned)
    const size_t histPartOff = 0;
    const size_t histPartBytes = ((size_t)HBLK * MAXNB * 4 + 255) & ~(size_t)255;  // 256 KB
    const size_t offsetsOff = histPartOff + histPartBytes;
    const size_t offsetsBytes = ((size_t)(MAXNB + 1) * 4 + 255) & ~(size_t)255;
    const size_t ticketOff = offsetsOff + offsetsBytes;
    const size_t ticketBytes = ((size_t)MAXNB * 4 + 255) & ~(size_t)255;
    const size_t csrOff = ticketOff + ticketBytes;
    const size_t csrBytes = ((size_t)E * 8 + 255) & ~(size_t)255;
    const size_t ubOff = csrOff + csrBytes;
    const size_t ubBytes = ((size_t)N * NFEAT * 2 + 255) & ~(size_t)255;
    const size_t totalWs = ubOff + ubBytes;

    if (ws_size < totalWs || NBH > MAXNB - 1) {
        zero_out_kernel<<<(out_size + 255) / 256, 256, 0, stream>>>(out, out_size);
        long long threads_total = (long long)E * 8;
        scatter_lap_kernel<<<(unsigned)((threads_total + 255) / 256), 256, 0, stream>>>(
            (const float4*)u, w, row, col, out, E);
        return;
    }

    char* ws = (char*)d_ws;
    int* hist_part = (int*)(ws + histPartOff);
    int* offsets = (int*)(ws + offsetsOff);
    int* ticket = (int*)(ws + ticketOff);
    uint2* csr = (uint2*)(ws + csrOff);
    ushort4* ub = (ushort4*)(ws + ubOff);

    // 1: private histograms + ticket zeroing (64 blocks, short)
    hist_kernel<<<HBLK, 512, 0, stream>>>(row, hist_part, ticket, E);

    // 2: fill blocks first, conv blocks backfill idle SIMDs
    int n4 = N * (NFEAT / 4);
    int convBlocks = (n4 + 511) / 512;
    const int nChunks = (E + CH - 1) / CH;
    fill_conv_kernel<<<nChunks + convBlocks, 512, 0, stream>>>(row, col, w, hist_part,
                                                               ticket, offsets, csr,
                                                               (const float4*)u, ub,
                                                               n4, E, nChunks);

    // 3: one block per half-bucket segment
    node_half_kernel<<<NBH, 512, 0, stream>>>(ub, (const float4*)u, offsets, csr,
                                              (float4*)out, N);
}

// Round 6
// 158.810 us; speedup vs baseline: 1.0471x; 1.0471x over previous
//
#include <hip/hip_runtime.h>

// DiffusionMLS: out[row[e]] += w[e]*(u[col[e]] - u[row[e]]), F=32 fp32.
// Round 20: node accumulate loop TRANSPOSED (lane = slot x feat -> slot owns
// a whole node).
//  - r19 post-mortem: removing the 2nd csr pass was NEUTRAL -> hist/permute
//    passes already TLP-hidden; cost is the accumulate loop itself.
//  - old: 8 slots share a node (2 gather rounds) then 5-step shfl_xor reduce
//    per node, 16 nodes/wave = 32 rounds + 16 serial DS-op drains; 7/8 lanes
//    masked at store.
//  - new: lane (s=lane>>3, f4=lane&7); slot s walks node g*8+s alone. se[i]
//    is an 8-lane LDS broadcast; ub gathers are independent (vmcnt
//    pipelining); NO shuffle reduce; stores fully coalesced (1KB/wave).
//  - everything else identical to r19.
// Pipeline: 1) hist+ticket-zero  2) fill multisplit + conv backfill  3) node.

#define NFEAT 32
#define BUCKET_BITS 7
#define HB 128               // nodes per segment; rowLow fits 7 bits
#define MAXNB 1024           // bucket cell count (NBH <= 1023)
#define CH 4096              // edges per fill chunk (multiple of 512)
#define HCAP 2560            // node-phase staging cap (= 5 * 512)
#define KSTASH (HCAP / 512)  // register stash depth
#define HBLK 64              // histogram partial blocks

typedef float nfloat4 __attribute__((ext_vector_type(4)));
typedef unsigned int nuint2 __attribute__((ext_vector_type(2)));

__device__ __forceinline__ float4 nt_load_f4(const float4* p) {
    nfloat4 v = __builtin_nontemporal_load((const nfloat4*)p);
    return make_float4(v.x, v.y, v.z, v.w);
}
__device__ __forceinline__ void nt_store_f4(float4* p, float4 v) {
    nfloat4 t = {v.x, v.y, v.z, v.w};
    __builtin_nontemporal_store(t, (nfloat4*)p);
}
__device__ __forceinline__ uint2 nt_load_u2(const uint2* p) {
    nuint2 v = __builtin_nontemporal_load((const nuint2*)p);
    uint2 r; r.x = v.x; r.y = v.y; return r;
}

// wave64 inclusive scan, no barriers
__device__ __forceinline__ int wave_incl_scan(int v, int lane) {
#pragma unroll
    for (int off = 1; off < 64; off <<= 1) {
        int t = __shfl_up(v, off, 64);
        if (lane >= off) v += t;
    }
    return v;
}

// ---- dispatch 1: 64 private histograms + ticket zeroing ----
__global__ __launch_bounds__(512) void hist_kernel(const int* __restrict__ row,
                                                   int* __restrict__ hist_part,
                                                   int* __restrict__ ticket,
                                                   int E) {
    __shared__ int h[MAXNB];
    int hb = blockIdx.x;
    if (hb == 0) {                      // zero-based tickets for fill phase
        ticket[threadIdx.x] = 0;
        ticket[threadIdx.x + 512] = 0;
    }
    for (int i = threadIdx.x; i < MAXNB; i += 512) h[i] = 0;
    __syncthreads();
    int stride = HBLK * 512;
    for (int e = hb * 512 + threadIdx.x; e < E; e += stride)
        atomicAdd(&h[__builtin_nontemporal_load(&row[e]) >> BUCKET_BITS], 1);
    __syncthreads();
    int* dst = hist_part + (size_t)hb * MAXNB;
    for (int i = threadIdx.x; i < MAXNB; i += 512) dst[i] = h[i];   // plain store
}

// ---- dispatch 2: fill blocks [0,nChunks) + conv blocks [nChunks, +convBlocks)
__global__ __launch_bounds__(512) void fill_conv_kernel(const int* __restrict__ row,
                                                        const int* __restrict__ col,
                                                        const float* __restrict__ w,
                                                        const int* __restrict__ hist_part,
                                                        int* __restrict__ ticket,
                                                        int* __restrict__ offsets,
                                                        uint2* __restrict__ csr,
                                                        const float4* __restrict__ u4,
                                                        ushort4* __restrict__ ub,
                                                        int n4, int E, int nChunks) {
    __shared__ int hist[MAXNB];           // 4K
    __shared__ int sc[MAXNB];             // 4K
    __shared__ int gb0[MAXNB];            // 4K
    __shared__ int wsumL[8];
    __shared__ int wsumG[8];
    __shared__ uint2 so[CH];              // 32K
    __shared__ unsigned short sbs[CH];    // 8K

    if ((int)blockIdx.x >= nChunks) {     // ---- conv block (pure streaming)
        int i = ((int)blockIdx.x - nChunks) * 512 + threadIdx.x;
        if (i < n4) {
            float4 v = nt_load_f4(&u4[i]);
            ushort4 o;
            unsigned x;
            x = __float_as_uint(v.x); x += 0x7fffu + ((x >> 16) & 1u); o.x = (unsigned short)(x >> 16);
            x = __float_as_uint(v.y); x += 0x7fffu + ((x >> 16) & 1u); o.y = (unsigned short)(x >> 16);
            x = __float_as_uint(v.z); x += 0x7fffu + ((x >> 16) & 1u); o.z = (unsigned short)(x >> 16);
            x = __float_as_uint(v.w); x += 0x7fffu + ((x >> 16) & 1u); o.w = (unsigned short)(x >> 16);
            ub[i] = o;
        }
        return;
    }

    int tid = threadIdx.x;
    int lane = tid & 63, wid = tid >> 6;
    int lo = blockIdx.x * CH;
    int n = min(E - lo, CH);
    bool full = (n == CH);

    hist[tid] = 0;
    hist[tid + 512] = 0;
    __syncthreads();

    // -- local hist (+ register row stash for full chunks)
    int rst[CH / 512];                    // static idx only (rule #20)
    if (full) {
#pragma unroll
        for (int k = 0; k < CH / 512; ++k) {
            int r = __builtin_nontemporal_load(&row[lo + tid + k * 512]);
            rst[k] = r;
            atomicAdd(&hist[r >> BUCKET_BITS], 1);
        }
    } else {
        for (int i = tid; i < n; i += 512)
            atomicAdd(&hist[__builtin_nontemporal_load(&row[lo + i]) >> BUCKET_BITS], 1);
    }

    // -- redundant global partial sum (L2-resident 256 KB; overlaps hist tail)
    int c0g = 0, c1g = 0;
    for (int p = 0; p < HBLK; ++p) {
        int2 v = ((const int2*)(hist_part + (size_t)p * MAXNB))[tid];
        c0g += v.x; c1g += v.y;
    }
    __syncthreads();                      // local hist complete

    int c0 = hist[2 * tid];
    int c1 = hist[2 * tid + 1];
    int pairL = c0 + c1;
    int pairG = c0g + c1g;
    int inclL = wave_incl_scan(pairL, lane);
    int inclG = wave_incl_scan(pairG, lane);
    if (lane == 63) { wsumL[wid] = inclL; wsumG[wid] = inclG; }
    __syncthreads();
    int baseL = 0, baseG = 0;
#pragma unroll
    for (int i = 0; i < 8; ++i) {
        int vl = wsumL[i], vg = wsumG[i];
        if (i < wid) { baseL += vl; baseG += vg; }
    }
    inclL += baseL;
    inclG += baseG;
    int exclL = inclL - pairL;
    sc[2 * tid] = exclL;
    sc[2 * tid + 1] = exclL + c0;
    int gE0 = inclG - pairG;              // global exclusive offset, cell 2t
    int gE1 = gE0 + c0g;                  // cell 2t+1

    if (blockIdx.x == 0) {                // offsets for node phase
        offsets[2 * tid] = gE0;
        offsets[2 * tid + 1] = gE1;
        if (tid == 511) offsets[MAXNB] = inclG;   // = E
    }

    int g0 = gE0 + (c0 ? atomicAdd(&ticket[2 * tid], c0) : 0);
    int g1 = gE1 + (c1 ? atomicAdd(&ticket[2 * tid + 1], c1) : 0);
    gb0[2 * tid] = g0;
    gb0[2 * tid + 1] = g1;
    hist[2 * tid] = g0;                   // arrival cursor
    hist[2 * tid + 1] = g1;
    __syncthreads();

    // -- multisplit into LDS staging
    if (full) {
#pragma unroll
        for (int k = 0; k < CH / 512; ++k) {
            int i = tid + k * 512;
            int r = rst[k];
            unsigned c = (unsigned)__builtin_nontemporal_load(&col[lo + i]);
            float wt = __builtin_nontemporal_load(&w[lo + i]);
            int b = r >> BUCKET_BITS;
            uint2 p;
            p.x = ((unsigned)(r & (HB - 1)) << 25) | c;   // rowLow:7 | col:25
            p.y = __float_as_uint(wt);
            int d = atomicAdd(&hist[b], 1);
            int pos = sc[b] + (d - gb0[b]);
            so[pos] = p;
            sbs[pos] = (unsigned short)b;
        }
    } else {
        for (int i = tid; i < n; i += 512) {
            int r = __builtin_nontemporal_load(&row[lo + i]);
            unsigned c = (unsigned)__builtin_nontemporal_load(&col[lo + i]);
            float wt = __builtin_nontemporal_load(&w[lo + i]);
            int b = r >> BUCKET_BITS;
            uint2 p;
            p.x = ((unsigned)(r & (HB - 1)) << 25) | c;
            p.y = __float_as_uint(wt);
            int d = atomicAdd(&hist[b], 1);
            int pos = sc[b] + (d - gb0[b]);
            so[pos] = p;
            sbs[pos] = (unsigned short)b;
        }
    }
    __syncthreads();

    // -- coalesced-run writeout
    for (int i = tid; i < n; i += 512) {
        int b = sbs[i];
        csr[gb0[b] + (i - sc[b])] = so[i];
    }
}

// ---- dispatch 3: per-segment counting sort + per-lane node accumulation ----
__global__ __launch_bounds__(512) void node_half_kernel(const ushort4* __restrict__ ub,
                                                        const float4* __restrict__ u4,
                                                        const int* __restrict__ offsets,
                                                        const uint2* __restrict__ csr,
                                                        float4* __restrict__ out4, int N) {
    __shared__ uint2 se[HCAP];          // 20.5 KB (fallback: f32 tile 16 KB)
    __shared__ int hist[HB];
    __shared__ int starts[HB + 1];
    __shared__ int sc[HB];

    int b = blockIdx.x;
    int tid = threadIdx.x;
    int start = offsets[b];
    int end = offsets[b + 1];
    int cnt = end - start;

    if (tid < HB) hist[tid] = 0;
    __syncthreads();

    if (cnt <= HCAP) {
        uint2 rst[KSTASH];              // csr register stash
#pragma unroll
        for (int k = 0; k < KSTASH; ++k) {
            int i = start + tid + k * 512;
            if (i < end) {
                uint2 p = nt_load_u2(&csr[i]);
                rst[k] = p;
                atomicAdd(&hist[p.x >> 25], 1);
            }
        }
        __syncthreads();
        int myc = (tid < HB) ? hist[tid] : 0;
        int lane = tid & 63;
        int incl = wave_incl_scan(myc, lane);
        if (lane == 63) sc[tid >> 6] = incl;   // only waves 0-1 carry real data
        __syncthreads();
        if (tid < HB) {
            if (tid >= 64) incl += sc[0];
            int excl = incl - myc;
            starts[tid] = excl;
            hist[tid] = excl;       // cursor
            if (tid == HB - 1) starts[HB] = incl;
        }
        __syncthreads();
#pragma unroll
        for (int k = 0; k < KSTASH; ++k) {
            int i = start + tid + k * 512;
            if (i < end) {
                uint2 p = rst[k];
                int pos = atomicAdd(&hist[p.x >> 25], 1);
                se[pos] = p;
            }
        }
        __syncthreads();

        // ---- transposed accumulate: slot s owns node g*8+s entirely ----
        int wave = tid >> 6;
        int f4 = lane & 7;          // feature float4 index
        int s = lane >> 3;          // node-within-group
        for (int g = wave; g < HB / 8; g += 8) {   // 16 groups, 2 per wave
            int node = g * 8 + s;
            int s0 = starts[node];
            int s1 = starts[node + 1];
            float4 acc = make_float4(0.f, 0.f, 0.f, 0.f);
            float ws_ = 0.f;
            for (int i = s0; i < s1; ++i) {
                uint2 p = se[i];    // 8-lane broadcast within f4-group
                int c = (int)(p.x & 0x01FFFFFFu);
                float wt = __uint_as_float(p.y);
                ushort4 us = ub[(size_t)c * 8 + f4];
                acc.x += wt * __uint_as_float((unsigned)us.x << 16);
                acc.y += wt * __uint_as_float((unsigned)us.y << 16);
                acc.z += wt * __uint_as_float((unsigned)us.z << 16);
                acc.w += wt * __uint_as_float((unsigned)us.w << 16);
                ws_ += wt;
            }
            int glob = b * HB + node;
            if (glob < N) {
                float4 ur = nt_load_f4(&u4[(size_t)glob * 8 + f4]);
                float4 o;
                o.x = acc.x - ws_ * ur.x;
                o.y = acc.y - ws_ * ur.y;
                o.z = acc.z - ws_ * ur.z;
                o.w = acc.w - ws_ * ur.w;
                nt_store_f4(&out4[(size_t)glob * 8 + f4], o);
            }
        }
    } else {
        float* tile = (float*)se;   // HB*32 floats
        float* wsumf = (float*)sc;
        for (int i = tid; i < HB * NFEAT; i += 512) tile[i] = 0.f;
        if (tid < HB) wsumf[tid] = 0.f;
        __syncthreads();
        int f4 = tid & 7;
        for (int i = start + (tid >> 3); i < end; i += 64) {
            uint2 p = nt_load_u2(&csr[i]);
            int rl = (int)(p.x >> 25);
            int c = (int)(p.x & 0x01FFFFFFu);
            float wt = __uint_as_float(p.y);
            ushort4 us = ub[(size_t)c * 8 + f4];
            float* t = &tile[rl * NFEAT + f4 * 4];
            atomicAdd(t + 0, wt * __uint_as_float((unsigned)us.x << 16));
            atomicAdd(t + 1, wt * __uint_as_float((unsigned)us.y << 16));
            atomicAdd(t + 2, wt * __uint_as_float((unsigned)us.z << 16));
            atomicAdd(t + 3, wt * __uint_as_float((unsigned)us.w << 16));
            if (f4 == 0) atomicAdd(&wsumf[rl], wt);
        }
        __syncthreads();
#pragma unroll
        for (int pass = 0; pass < 2; ++pass) {
            int idx = pass * 512 + tid;
            int node = idx >> 3;
            int ff = idx & 7;
            int glob = b * HB + node;
            if (glob < N) {
                float4 ur = nt_load_f4(&u4[(size_t)glob * 8 + ff]);
                float ws_ = wsumf[node];
                const float* t = &tile[node * NFEAT + ff * 4];
                float4 o;
                o.x = t[0] - ws_ * ur.x;
                o.y = t[1] - ws_ * ur.y;
                o.z = t[2] - ws_ * ur.z;
                o.w = t[3] - ws_ * ur.w;
                nt_store_f4(&out4[(size_t)glob * 8 + ff], o);
            }
        }
    }
}

// ---------------- fallback (atomic path) ----------------

__global__ __launch_bounds__(256) void zero_out_kernel(float* __restrict__ out, int n) {
    int i = blockIdx.x * blockDim.x + threadIdx.x;
    if (i < n) out[i] = 0.0f;
}

__global__ __launch_bounds__(256) void scatter_lap_kernel(const float4* __restrict__ u4,
                                                          const float* __restrict__ w,
                                                          const int* __restrict__ row,
                                                          const int* __restrict__ col,
                                                          float* __restrict__ out, int n_edges) {
    int tid = blockIdx.x * blockDim.x + threadIdx.x;
    int e = tid >> 3;
    int f4 = tid & 7;
    if (e >= n_edges) return;
    int r = row[e];
    int c = col[e];
    float wt = w[e];
    float4 uc = u4[(size_t)c * 8 + f4];
    float4 ur = u4[(size_t)r * 8 + f4];
    float* o = out + (size_t)r * NFEAT + f4 * 4;
    atomicAdd(o + 0, wt * (uc.x - ur.x));
    atomicAdd(o + 1, wt * (uc.y - ur.y));
    atomicAdd(o + 2, wt * (uc.z - ur.z));
    atomicAdd(o + 3, wt * (uc.w - ur.w));
}

extern "C" void kernel_launch(void* const* d_in, const int* in_sizes, int n_in,
                              void* d_out, int out_size, void* d_ws, size_t ws_size,
                              hipStream_t stream) {
    const float* u = (const float*)d_in[0];
    const float* w = (const float*)d_in[1];
    const int* ei = (const int*)d_in[2];  // [2, E] int32
    float* out = (float*)d_out;

    const int E = in_sizes[1];
    const int N = out_size / NFEAT;
    const int* row = ei;
    const int* col = ei + E;

    const int NBH = (N + HB - 1) >> BUCKET_BITS;

    // workspace layout (256-B aligned)
    const size_t histPartOff = 0;
    const size_t histPartBytes = ((size_t)HBLK * MAXNB * 4 + 255) & ~(size_t)255;  // 256 KB
    const size_t offsetsOff = histPartOff + histPartBytes;
    const size_t offsetsBytes = ((size_t)(MAXNB + 1) * 4 + 255) & ~(size_t)255;
    const size_t ticketOff = offsetsOff + offsetsBytes;
    const size_t ticketBytes = ((size_t)MAXNB * 4 + 255) & ~(size_t)255;
    const size_t csrOff = ticketOff + ticketBytes;
    const size_t csrBytes = ((size_t)E * 8 + 255) & ~(size_t)255;
    const size_t ubOff = csrOff + csrBytes;
    const size_t ubBytes = ((size_t)N * NFEAT * 2 + 255) & ~(size_t)255;
    const size_t totalWs = ubOff + ubBytes;

    if (ws_size < totalWs || NBH > MAXNB - 1) {
        zero_out_kernel<<<(out_size + 255) / 256, 256, 0, stream>>>(out, out_size);
        long long threads_total = (long long)E * 8;
        scatter_lap_kernel<<<(unsigned)((threads_total + 255) / 256), 256, 0, stream>>>(
            (const float4*)u, w, row, col, out, E);
        return;
    }

    char* ws = (char*)d_ws;
    int* hist_part = (int*)(ws + histPartOff);
    int* offsets = (int*)(ws + offsetsOff);
    int* ticket = (int*)(ws + ticketOff);
    uint2* csr = (uint2*)(ws + csrOff);
    ushort4* ub = (ushort4*)(ws + ubOff);

    // 1: private histograms + ticket zeroing (64 blocks, short)
    hist_kernel<<<HBLK, 512, 0, stream>>>(row, hist_part, ticket, E);

    // 2: fill blocks first, conv blocks backfill idle SIMDs
    int n4 = N * (NFEAT / 4);
    int convBlocks = (n4 + 511) / 512;
    const int nChunks = (E + CH - 1) / CH;
    fill_conv_kernel<<<nChunks + convBlocks, 512, 0, stream>>>(row, col, w, hist_part,
                                                               ticket, offsets, csr,
                                                               (const float4*)u, ub,
                                                               n4, E, nChunks);

    // 3: one block per half-bucket segment
    node_half_kernel<<<NBH, 512, 0, stream>>>(ub, (const float4*)u, offsets, csr,
                                              (float4*)out, N);
}

// Round 7
// 139.711 us; speedup vs baseline: 1.1902x; 1.1367x over previous
//
#include <hip/hip_runtime.h>

// DiffusionMLS: out[row[e]] += w[e]*(u[col[e]] - u[row[e]]), F=32 fp32.
// Round 21: ILP polish on the two measured-hot loops (no structural change).
//  - r20 post-mortem: transposed accumulate -7.5us (158.8 best). node+fill
//    now both <45us (below harness poison fills in top-5).
//  - node gather loop: manual unroll-by-2, DUAL accumulators. One outstanding
//    ub gather per lane -> two; dependent rounds ~16 -> ~8 (dynamic trip
//    count blocks compiler unrolling; acc chain serialized the loop).
//  - hist_kernel: int4 row loads (16B/lane, G13), iters 49 -> 12.
//  - everything else identical to r20.
// Pipeline: 1) hist+ticket-zero  2) fill multisplit + conv backfill  3) node.

#define NFEAT 32
#define BUCKET_BITS 7
#define HB 128               // nodes per segment; rowLow fits 7 bits
#define MAXNB 1024           // bucket cell count (NBH <= 1023)
#define CH 4096              // edges per fill chunk (multiple of 512)
#define HCAP 2560            // node-phase staging cap (= 5 * 512)
#define KSTASH (HCAP / 512)  // register stash depth
#define HBLK 64              // histogram partial blocks

typedef float nfloat4 __attribute__((ext_vector_type(4)));
typedef unsigned int nuint2 __attribute__((ext_vector_type(2)));

__device__ __forceinline__ float4 nt_load_f4(const float4* p) {
    nfloat4 v = __builtin_nontemporal_load((const nfloat4*)p);
    return make_float4(v.x, v.y, v.z, v.w);
}
__device__ __forceinline__ void nt_store_f4(float4* p, float4 v) {
    nfloat4 t = {v.x, v.y, v.z, v.w};
    __builtin_nontemporal_store(t, (nfloat4*)p);
}
__device__ __forceinline__ uint2 nt_load_u2(const uint2* p) {
    nuint2 v = __builtin_nontemporal_load((const nuint2*)p);
    uint2 r; r.x = v.x; r.y = v.y; return r;
}

// wave64 inclusive scan, no barriers
__device__ __forceinline__ int wave_incl_scan(int v, int lane) {
#pragma unroll
    for (int off = 1; off < 64; off <<= 1) {
        int t = __shfl_up(v, off, 64);
        if (lane >= off) v += t;
    }
    return v;
}

// ---- dispatch 1: 64 private histograms (int4 loads) + ticket zeroing ----
__global__ __launch_bounds__(512) void hist_kernel(const int* __restrict__ row,
                                                   int* __restrict__ hist_part,
                                                   int* __restrict__ ticket,
                                                   int E) {
    __shared__ int h[MAXNB];
    int hb = blockIdx.x;
    if (hb == 0) {                      // zero-based tickets for fill phase
        ticket[threadIdx.x] = 0;
        ticket[threadIdx.x + 512] = 0;
    }
    for (int i = threadIdx.x; i < MAXNB; i += 512) h[i] = 0;
    __syncthreads();
    // 2048-edge contiguous span per block per iteration, int4 per lane
    int span = hb;
    int nspan = (E + 2047) >> 11;
    for (; span < nspan; span += HBLK) {
        int e = (span << 11) + threadIdx.x * 4;
        if (e + 3 < E) {
            int4 r4 = *(const int4*)(row + e);
            atomicAdd(&h[r4.x >> BUCKET_BITS], 1);
            atomicAdd(&h[r4.y >> BUCKET_BITS], 1);
            atomicAdd(&h[r4.z >> BUCKET_BITS], 1);
            atomicAdd(&h[r4.w >> BUCKET_BITS], 1);
        } else {
            for (int k = 0; k < 4; ++k)
                if (e + k < E)
                    atomicAdd(&h[row[e + k] >> BUCKET_BITS], 1);
        }
    }
    __syncthreads();
    int* dst = hist_part + (size_t)hb * MAXNB;
    for (int i = threadIdx.x; i < MAXNB; i += 512) dst[i] = h[i];   // plain store
}

// ---- dispatch 2: fill blocks [0,nChunks) + conv blocks [nChunks, +convBlocks)
__global__ __launch_bounds__(512) void fill_conv_kernel(const int* __restrict__ row,
                                                        const int* __restrict__ col,
                                                        const float* __restrict__ w,
                                                        const int* __restrict__ hist_part,
                                                        int* __restrict__ ticket,
                                                        int* __restrict__ offsets,
                                                        uint2* __restrict__ csr,
                                                        const float4* __restrict__ u4,
                                                        ushort4* __restrict__ ub,
                                                        int n4, int E, int nChunks) {
    __shared__ int hist[MAXNB];           // 4K
    __shared__ int sc[MAXNB];             // 4K
    __shared__ int gb0[MAXNB];            // 4K
    __shared__ int wsumL[8];
    __shared__ int wsumG[8];
    __shared__ uint2 so[CH];              // 32K
    __shared__ unsigned short sbs[CH];    // 8K

    if ((int)blockIdx.x >= nChunks) {     // ---- conv block (pure streaming)
        int i = ((int)blockIdx.x - nChunks) * 512 + threadIdx.x;
        if (i < n4) {
            float4 v = nt_load_f4(&u4[i]);
            ushort4 o;
            unsigned x;
            x = __float_as_uint(v.x); x += 0x7fffu + ((x >> 16) & 1u); o.x = (unsigned short)(x >> 16);
            x = __float_as_uint(v.y); x += 0x7fffu + ((x >> 16) & 1u); o.y = (unsigned short)(x >> 16);
            x = __float_as_uint(v.z); x += 0x7fffu + ((x >> 16) & 1u); o.z = (unsigned short)(x >> 16);
            x = __float_as_uint(v.w); x += 0x7fffu + ((x >> 16) & 1u); o.w = (unsigned short)(x >> 16);
            ub[i] = o;
        }
        return;
    }

    int tid = threadIdx.x;
    int lane = tid & 63, wid = tid >> 6;
    int lo = blockIdx.x * CH;
    int n = min(E - lo, CH);
    bool full = (n == CH);

    hist[tid] = 0;
    hist[tid + 512] = 0;
    __syncthreads();

    // -- local hist (+ register row stash for full chunks)
    int rst[CH / 512];                    // static idx only (rule #20)
    if (full) {
#pragma unroll
        for (int k = 0; k < CH / 512; ++k) {
            int r = __builtin_nontemporal_load(&row[lo + tid + k * 512]);
            rst[k] = r;
            atomicAdd(&hist[r >> BUCKET_BITS], 1);
        }
    } else {
        for (int i = tid; i < n; i += 512)
            atomicAdd(&hist[__builtin_nontemporal_load(&row[lo + i]) >> BUCKET_BITS], 1);
    }

    // -- redundant global partial sum (L2-resident 256 KB; overlaps hist tail)
    int c0g = 0, c1g = 0;
    for (int p = 0; p < HBLK; ++p) {
        int2 v = ((const int2*)(hist_part + (size_t)p * MAXNB))[tid];
        c0g += v.x; c1g += v.y;
    }
    __syncthreads();                      // local hist complete

    int c0 = hist[2 * tid];
    int c1 = hist[2 * tid + 1];
    int pairL = c0 + c1;
    int pairG = c0g + c1g;
    int inclL = wave_incl_scan(pairL, lane);
    int inclG = wave_incl_scan(pairG, lane);
    if (lane == 63) { wsumL[wid] = inclL; wsumG[wid] = inclG; }
    __syncthreads();
    int baseL = 0, baseG = 0;
#pragma unroll
    for (int i = 0; i < 8; ++i) {
        int vl = wsumL[i], vg = wsumG[i];
        if (i < wid) { baseL += vl; baseG += vg; }
    }
    inclL += baseL;
    inclG += baseG;
    int exclL = inclL - pairL;
    sc[2 * tid] = exclL;
    sc[2 * tid + 1] = exclL + c0;
    int gE0 = inclG - pairG;              // global exclusive offset, cell 2t
    int gE1 = gE0 + c0g;                  // cell 2t+1

    if (blockIdx.x == 0) {                // offsets for node phase
        offsets[2 * tid] = gE0;
        offsets[2 * tid + 1] = gE1;
        if (tid == 511) offsets[MAXNB] = inclG;   // = E
    }

    int g0 = gE0 + (c0 ? atomicAdd(&ticket[2 * tid], c0) : 0);
    int g1 = gE1 + (c1 ? atomicAdd(&ticket[2 * tid + 1], c1) : 0);
    gb0[2 * tid] = g0;
    gb0[2 * tid + 1] = g1;
    hist[2 * tid] = g0;                   // arrival cursor
    hist[2 * tid + 1] = g1;
    __syncthreads();

    // -- multisplit into LDS staging
    if (full) {
#pragma unroll
        for (int k = 0; k < CH / 512; ++k) {
            int i = tid + k * 512;
            int r = rst[k];
            unsigned c = (unsigned)__builtin_nontemporal_load(&col[lo + i]);
            float wt = __builtin_nontemporal_load(&w[lo + i]);
            int b = r >> BUCKET_BITS;
            uint2 p;
            p.x = ((unsigned)(r & (HB - 1)) << 25) | c;   // rowLow:7 | col:25
            p.y = __float_as_uint(wt);
            int d = atomicAdd(&hist[b], 1);
            int pos = sc[b] + (d - gb0[b]);
            so[pos] = p;
            sbs[pos] = (unsigned short)b;
        }
    } else {
        for (int i = tid; i < n; i += 512) {
            int r = __builtin_nontemporal_load(&row[lo + i]);
            unsigned c = (unsigned)__builtin_nontemporal_load(&col[lo + i]);
            float wt = __builtin_nontemporal_load(&w[lo + i]);
            int b = r >> BUCKET_BITS;
            uint2 p;
            p.x = ((unsigned)(r & (HB - 1)) << 25) | c;
            p.y = __float_as_uint(wt);
            int d = atomicAdd(&hist[b], 1);
            int pos = sc[b] + (d - gb0[b]);
            so[pos] = p;
            sbs[pos] = (unsigned short)b;
        }
    }
    __syncthreads();

    // -- coalesced-run writeout
    for (int i = tid; i < n; i += 512) {
        int b = sbs[i];
        csr[gb0[b] + (i - sc[b])] = so[i];
    }
}

// ---- dispatch 3: per-segment counting sort + per-lane node accumulation ----
__global__ __launch_bounds__(512) void node_half_kernel(const ushort4* __restrict__ ub,
                                                        const float4* __restrict__ u4,
                                                        const int* __restrict__ offsets,
                                                        const uint2* __restrict__ csr,
                                                        float4* __restrict__ out4, int N) {
    __shared__ uint2 se[HCAP];          // 20.5 KB (fallback: f32 tile 16 KB)
    __shared__ int hist[HB];
    __shared__ int starts[HB + 1];
    __shared__ int sc[HB];

    int b = blockIdx.x;
    int tid = threadIdx.x;
    int start = offsets[b];
    int end = offsets[b + 1];
    int cnt = end - start;

    if (tid < HB) hist[tid] = 0;
    __syncthreads();

    if (cnt <= HCAP) {
        uint2 rst[KSTASH];              // csr register stash
#pragma unroll
        for (int k = 0; k < KSTASH; ++k) {
            int i = start + tid + k * 512;
            if (i < end) {
                uint2 p = nt_load_u2(&csr[i]);
                rst[k] = p;
                atomicAdd(&hist[p.x >> 25], 1);
            }
        }
        __syncthreads();
        int myc = (tid < HB) ? hist[tid] : 0;
        int lane = tid & 63;
        int incl = wave_incl_scan(myc, lane);
        if (lane == 63) sc[tid >> 6] = incl;   // only waves 0-1 carry real data
        __syncthreads();
        if (tid < HB) {
            if (tid >= 64) incl += sc[0];
            int excl = incl - myc;
            starts[tid] = excl;
            hist[tid] = excl;       // cursor
            if (tid == HB - 1) starts[HB] = incl;
        }
        __syncthreads();
#pragma unroll
        for (int k = 0; k < KSTASH; ++k) {
            int i = start + tid + k * 512;
            if (i < end) {
                uint2 p = rst[k];
                int pos = atomicAdd(&hist[p.x >> 25], 1);
                se[pos] = p;
            }
        }
        __syncthreads();

        // ---- transposed accumulate, unroll x2 with dual accumulators ----
        int wave = tid >> 6;
        int f4 = lane & 7;          // feature float4 index
        int s = lane >> 3;          // node-within-group
        for (int g = wave; g < HB / 8; g += 8) {   // 16 groups, 2 per wave
            int node = g * 8 + s;
            int s0 = starts[node];
            int s1 = starts[node + 1];
            float4 accA = make_float4(0.f, 0.f, 0.f, 0.f);
            float4 accB = make_float4(0.f, 0.f, 0.f, 0.f);
            float wsA = 0.f, wsB = 0.f;
            int i = s0;
            for (; i + 1 < s1; i += 2) {
                uint2 pa = se[i];
                uint2 pb = se[i + 1];
                int ca = (int)(pa.x & 0x01FFFFFFu);
                int cb = (int)(pb.x & 0x01FFFFFFu);
                float wa = __uint_as_float(pa.y);
                float wb = __uint_as_float(pb.y);
                ushort4 ua = ub[(size_t)ca * 8 + f4];   // two independent
                ushort4 ubv = ub[(size_t)cb * 8 + f4];  // gathers in flight
                accA.x += wa * __uint_as_float((unsigned)ua.x << 16);
                accA.y += wa * __uint_as_float((unsigned)ua.y << 16);
                accA.z += wa * __uint_as_float((unsigned)ua.z << 16);
                accA.w += wa * __uint_as_float((unsigned)ua.w << 16);
                wsA += wa;
                accB.x += wb * __uint_as_float((unsigned)ubv.x << 16);
                accB.y += wb * __uint_as_float((unsigned)ubv.y << 16);
                accB.z += wb * __uint_as_float((unsigned)ubv.z << 16);
                accB.w += wb * __uint_as_float((unsigned)ubv.w << 16);
                wsB += wb;
            }
            if (i < s1) {
                uint2 p = se[i];
                int c = (int)(p.x & 0x01FFFFFFu);
                float wt = __uint_as_float(p.y);
                ushort4 us = ub[(size_t)c * 8 + f4];
                accA.x += wt * __uint_as_float((unsigned)us.x << 16);
                accA.y += wt * __uint_as_float((unsigned)us.y << 16);
                accA.z += wt * __uint_as_float((unsigned)us.z << 16);
                accA.w += wt * __uint_as_float((unsigned)us.w << 16);
                wsA += wt;
            }
            float4 acc;
            acc.x = accA.x + accB.x;
            acc.y = accA.y + accB.y;
            acc.z = accA.z + accB.z;
            acc.w = accA.w + accB.w;
            float ws_ = wsA + wsB;
            int glob = b * HB + node;
            if (glob < N) {
                float4 ur = nt_load_f4(&u4[(size_t)glob * 8 + f4]);
                float4 o;
                o.x = acc.x - ws_ * ur.x;
                o.y = acc.y - ws_ * ur.y;
                o.z = acc.z - ws_ * ur.z;
                o.w = acc.w - ws_ * ur.w;
                nt_store_f4(&out4[(size_t)glob * 8 + f4], o);
            }
        }
    } else {
        float* tile = (float*)se;   // HB*32 floats
        float* wsumf = (float*)sc;
        for (int i = tid; i < HB * NFEAT; i += 512) tile[i] = 0.f;
        if (tid < HB) wsumf[tid] = 0.f;
        __syncthreads();
        int f4 = tid & 7;
        for (int i = start + (tid >> 3); i < end; i += 64) {
            uint2 p = nt_load_u2(&csr[i]);
            int rl = (int)(p.x >> 25);
            int c = (int)(p.x & 0x01FFFFFFu);
            float wt = __uint_as_float(p.y);
            ushort4 us = ub[(size_t)c * 8 + f4];
            float* t = &tile[rl * NFEAT + f4 * 4];
            atomicAdd(t + 0, wt * __uint_as_float((unsigned)us.x << 16));
            atomicAdd(t + 1, wt * __uint_as_float((unsigned)us.y << 16));
            atomicAdd(t + 2, wt * __uint_as_float((unsigned)us.z << 16));
            atomicAdd(t + 3, wt * __uint_as_float((unsigned)us.w << 16));
            if (f4 == 0) atomicAdd(&wsumf[rl], wt);
        }
        __syncthreads();
#pragma unroll
        for (int pass = 0; pass < 2; ++pass) {
            int idx = pass * 512 + tid;
            int node = idx >> 3;
            int ff = idx & 7;
            int glob = b * HB + node;
            if (glob < N) {
                float4 ur = nt_load_f4(&u4[(size_t)glob * 8 + ff]);
                float ws_ = wsumf[node];
                const float* t = &tile[node * NFEAT + ff * 4];
                float4 o;
                o.x = t[0] - ws_ * ur.x;
                o.y = t[1] - ws_ * ur.y;
                o.z = t[2] - ws_ * ur.z;
                o.w = t[3] - ws_ * ur.w;
                nt_store_f4(&out4[(size_t)glob * 8 + ff], o);
            }
        }
    }
}

// ---------------- fallback (atomic path) ----------------

__global__ __launch_bounds__(256) void zero_out_kernel(float* __restrict__ out, int n) {
    int i = blockIdx.x * blockDim.x + threadIdx.x;
    if (i < n) out[i] = 0.0f;
}

__global__ __launch_bounds__(256) void scatter_lap_kernel(const float4* __restrict__ u4,
                                                          const float* __restrict__ w,
                                                          const int* __restrict__ row,
                                                          const int* __restrict__ col,
                                                          float* __restrict__ out, int n_edges) {
    int tid = blockIdx.x * blockDim.x + threadIdx.x;
    int e = tid >> 3;
    int f4 = tid & 7;
    if (e >= n_edges) return;
    int r = row[e];
    int c = col[e];
    float wt = w[e];
    float4 uc = u4[(size_t)c * 8 + f4];
    float4 ur = u4[(size_t)r * 8 + f4];
    float* o = out + (size_t)r * NFEAT + f4 * 4;
    atomicAdd(o + 0, wt * (uc.x - ur.x));
    atomicAdd(o + 1, wt * (uc.y - ur.y));
    atomicAdd(o + 2, wt * (uc.z - ur.z));
    atomicAdd(o + 3, wt * (uc.w - ur.w));
}

extern "C" void kernel_launch(void* const* d_in, const int* in_sizes, int n_in,
                              void* d_out, int out_size, void* d_ws, size_t ws_size,
                              hipStream_t stream) {
    const float* u = (const float*)d_in[0];
    const float* w = (const float*)d_in[1];
    const int* ei = (const int*)d_in[2];  // [2, E] int32
    float* out = (float*)d_out;

    const int E = in_sizes[1];
    const int N = out_size / NFEAT;
    const int* row = ei;
    const int* col = ei + E;

    const int NBH = (N + HB - 1) >> BUCKET_BITS;

    // workspace layout (256-B aligned)
    const size_t histPartOff = 0;
    const size_t histPartBytes = ((size_t)HBLK * MAXNB * 4 + 255) & ~(size_t)255;  // 256 KB
    const size_t offsetsOff = histPartOff + histPartBytes;
    const size_t offsetsBytes = ((size_t)(MAXNB + 1) * 4 + 255) & ~(size_t)255;
    const size_t ticketOff = offsetsOff + offsetsBytes;
    const size_t ticketBytes = ((size_t)MAXNB * 4 + 255) & ~(size_t)255;
    const size_t csrOff = ticketOff + ticketBytes;
    const size_t csrBytes = ((size_t)E * 8 + 255) & ~(size_t)255;
    const size_t ubOff = csrOff + csrBytes;
    const size_t ubBytes = ((size_t)N * NFEAT * 2 + 255) & ~(size_t)255;
    const size_t totalWs = ubOff + ubBytes;

    if (ws_size < totalWs || NBH > MAXNB - 1) {
        zero_out_kernel<<<(out_size + 255) / 256, 256, 0, stream>>>(out, out_size);
        long long threads_total = (long long)E * 8;
        scatter_lap_kernel<<<(unsigned)((threads_total + 255) / 256), 256, 0, stream>>>(
            (const float4*)u, w, row, col, out, E);
        return;
    }

    char* ws = (char*)d_ws;
    int* hist_part = (int*)(ws + histPartOff);
    int* offsets = (int*)(ws + offsetsOff);
    int* ticket = (int*)(ws + ticketOff);
    uint2* csr = (uint2*)(ws + csrOff);
    ushort4* ub = (ushort4*)(ws + ubOff);

    // 1: private histograms + ticket zeroing (64 blocks, short)
    hist_kernel<<<HBLK, 512, 0, stream>>>(row, hist_part, ticket, E);

    // 2: fill blocks first, conv blocks backfill idle SIMDs
    int n4 = N * (NFEAT / 4);
    int convBlocks = (n4 + 511) / 512;
    const int nChunks = (E + CH - 1) / CH;
    fill_conv_kernel<<<nChunks + convBlocks, 512, 0, stream>>>(row, col, w, hist_part,
                                                               ticket, offsets, csr,
                                                               (const float4*)u, ub,
                                                               n4, E, nChunks);

    // 3: one block per half-bucket segment
    node_half_kernel<<<NBH, 512, 0, stream>>>(ub, (const float4*)u, offsets, csr,
                                              (float4*)out, N);
}